// Round 4
// baseline (115.239 us; speedup 1.0000x reference)
//
#include <hip/hip_runtime.h>
#include <hip/hip_bf16.h>
#include <stdint.h>

// Problem dims (fixed by reference)
#define R_TOTAL 1024      // B*S
#define I_DIM   4096
#define OUT_DIM 4096
#define N_STR   32
#define Q_DIM   128

typedef __attribute__((ext_vector_type(8))) __bf16 bf16x8;
typedef __attribute__((ext_vector_type(4))) float  f32x4;

__device__ __forceinline__ ushort f2bf(float f) {
    uint32_t u = __float_as_uint(f);
    uint32_t r = (u + 0x7fffu + ((u >> 16) & 1u)) >> 16;   // RNE
    return (ushort)r;
}

// expand 2 mask bits (2w, 2w+1) -> 32-bit AND-mask for a packed bf16 pair
__device__ __forceinline__ uint32_t bexp(uint32_t b, int w) {
    return ((b >> (2 * w)) & 1u) * 0xFFFFu | ((b >> (2 * w + 1)) & 1u) * 0xFFFF0000u;
}

__device__ __forceinline__ void async16(void* lds, const void* g) {
    __builtin_amdgcn_global_load_lds(
        (const __attribute__((address_space(1))) unsigned int*)g,
        (__attribute__((address_space(3))) unsigned int*)lds, 16, 0, 0);
}

// ================= shared device bodies (used by merged + standalone) ========

// W [I][OUT] f32 -> WT [OUT][I] bf16, one 64x64 tile
__device__ __forceinline__ void transpose_w_block(const float* __restrict__ W,
                                                  ushort* __restrict__ WT,
                                                  int c0, int i0, int t,
                                                  float (*tile)[65]) {
    {
        int dc4 = (t & 15) * 4;
        int di  = t >> 4;
        #pragma unroll
        for (int p = 0; p < 4; ++p) {
            int ii = di + p * 16;
            float4 v = *(const float4*)(W + (size_t)(i0 + ii) * OUT_DIM + c0 + dc4);
            tile[ii][dc4 + 0] = v.x; tile[ii][dc4 + 1] = v.y;
            tile[ii][dc4 + 2] = v.z; tile[ii][dc4 + 3] = v.w;
        }
    }
    __syncthreads();
    {
        int iq = (t & 15) * 4;
        int dc = t >> 4;
        #pragma unroll
        for (int p = 0; p < 4; ++p) {
            int cc = dc + p * 16;
            ushort4 o;
            o.x = f2bf(tile[iq + 0][cc]);
            o.y = f2bf(tile[iq + 1][cc]);
            o.z = f2bf(tile[iq + 2][cc]);
            o.w = f2bf(tile[iq + 3][cc]);
            *(ushort4*)(WT + (size_t)(c0 + cc) * I_DIM + i0 + iq) = o;
        }
    }
}

// XB = bf16(x-mu) + per-stripe bitmasks, one (rb, ib) block of 8 rows x 256 i
__device__ __forceinline__ void prep_block(const float* __restrict__ x,
                                           const float* __restrict__ mu,
                                           const float* __restrict__ th,
                                           ushort* __restrict__ XB,
                                           unsigned long long* __restrict__ MB64,
                                           int rb, int ib, int tid,
                                           unsigned long long* sMB) {
    int i = ib * 256 + tid;
    int lane = tid & 63;
    int wave = tid >> 6;

    float muv = mu[i];
    float ax[8];
    #pragma unroll
    for (int rr = 0; rr < 8; ++rr) {
        int r = rb * 8 + rr;
        float xo = x[(size_t)r * I_DIM + i] - muv;
        XB[(size_t)r * I_DIM + i] = f2bf(xo);
        ax[rr] = fabsf(xo);
    }
    for (int n4 = 0; n4 < 8; ++n4) {
        float4 tv = *(const float4*)(th + (size_t)i * N_STR + n4 * 4);
        #pragma unroll
        for (int j = 0; j < 4; ++j) {
            float t = (j == 0) ? tv.x : (j == 1) ? tv.y : (j == 2) ? tv.z : tv.w;
            int n = n4 * 4 + j;
            #pragma unroll
            for (int rr = 0; rr < 8; ++rr) {
                unsigned long long bal = __ballot(ax[rr] >= t);
                if (lane == 0) sMB[(n * 8 + rr) * 4 + wave] = bal;
            }
        }
    }
    __syncthreads();
    int n = tid >> 3, rr = tid & 7;
    const uint4* s = (const uint4*)&sMB[(n * 8 + rr) * 4];
    uint4* dst = (uint4*)((char*)MB64 + ((size_t)n * R_TOTAL + rb * 8 + rr) * 512 + ib * 32);
    dst[0] = s[0];
    dst[1] = s[1];
}

// ---------------- merged pre-pass: transpose_w (blocks 0..4095) + prep -------
__global__ __launch_bounds__(256) void k_prep3(const float* __restrict__ W,
                                               ushort* __restrict__ WT,
                                               const float* __restrict__ x,
                                               const float* __restrict__ mu,
                                               const float* __restrict__ th,
                                               ushort* __restrict__ XB,
                                               unsigned long long* __restrict__ MB64) {
    __shared__ __align__(16) float smem[64 * 65];   // 16.25 KB, reused by both
    int b = blockIdx.x;
    int t = threadIdx.x;
    if (b < 4096) {
        transpose_w_block(W, WT, (b & 63) * 64, (b >> 6) * 64, t,
                          (float (*)[65])smem);
    } else {
        b -= 4096;                      // 0..2047
        prep_block(x, mu, th, XB, MB64, b >> 4, b & 15, t,
                   (unsigned long long*)smem);
    }
}

// ---------------- standalone pre-passes (fallback path) ----------------------
__global__ __launch_bounds__(256) void k_transpose_th(const float* __restrict__ th,
                                                      float* __restrict__ thT) {
    int idx = blockIdx.x * 256 + threadIdx.x;
    int n = idx >> 12;
    int i = idx & 4095;
    thT[idx] = th[i * N_STR + n];
}

__global__ __launch_bounds__(256) void k_transpose_w(const float* __restrict__ W,
                                                     ushort* __restrict__ WT) {
    __shared__ float tile[64][65];
    transpose_w_block(W, WT, blockIdx.x * 64, blockIdx.y * 64, threadIdx.x, tile);
}

__global__ __launch_bounds__(256) void k_prep2(const float* __restrict__ x,
                                               const float* __restrict__ mu,
                                               const float* __restrict__ th,
                                               ushort* __restrict__ XB,
                                               unsigned long long* __restrict__ MB64) {
    __shared__ unsigned long long sMB[N_STR * 8 * 4];
    prep_block(x, mu, th, XB, MB64, blockIdx.x >> 4, blockIdx.x & 15,
               threadIdx.x, sMB);
}

// ---------------- main v4: 128x128 block, 4 waves of 64x64, split-K=2 --------
// grid 512, 256 thr, LDS 64KB -> 2 blocks/CU. LDS reads/MFMA = 0.5.
#define NT4 32   // K-steps of 64 per block (K=2048 per k-half)

__global__ __launch_bounds__(256, 2) void k_main4(const ushort* __restrict__ XB,
                                                  const ushort* __restrict__ WT,
                                                  const uint8_t* __restrict__ MB,
                                                  float* __restrict__ P0,
                                                  float* __restrict__ P1) {
    __shared__ ushort sA[2][128 * 64];   // 16 KB each
    __shared__ ushort sB[2][128 * 64];   // 16 KB each

    int bid  = blockIdx.x;               // 0..511
    int xcd  = bid & 7;
    int slot = bid >> 3;                 // 0..63
    int n    = xcd * 4 + (slot & 3);     // stripe (XCD-local group of 4)
    int rt   = (slot >> 2) & 7;          // row tile 0..7
    int kh   = slot >> 5;                // k-half 0..1
    int r0   = rt * 128;
    int k0   = kh * 2048;                // element offset in K
    int cbase = n * Q_DIM;
    float* P = kh ? P1 : P0;

    int tid  = threadIdx.x;
    int lane = tid & 63;
    int wave = tid >> 6;                 // 0..3
    int wr   = wave >> 1;                // 0..1 : 64-row group
    int wc   = wave & 1;                 // 0..1 : 64-col group
    int lrow = lane & 15;
    int lgrp = lane >> 4;

    // ---- A staging: 4 passes; pass p: row = p*32 + (tid>>3), 8 elems at (tid&7)*8
    const ushort*  pXA[4];
    const uint8_t* pMA[4];
    int awz[4];
    {
        int ar = tid >> 3;               // 0..31
        int ak = (tid & 7) * 8;          // elem offset
        #pragma unroll
        for (int p = 0; p < 4; ++p) {
            int row = p * 32 + ar;
            pXA[p] = XB + (size_t)(r0 + row) * I_DIM + k0 + ak;
            pMA[p] = MB + ((size_t)n * R_TOTAL + r0 + row) * 512 + (k0 >> 3) + (tid & 7);
            awz[p] = row * 128 + ((ak * 2) ^ ((row & 7) << 4));
        }
    }

    // ---- B staging: 4 async16 per thread (16 chunks of 1KB); pre-swizzled src
    const char* pBq[4];
    int ldsBo[4];
    #pragma unroll
    for (int q = 0; q < 4; ++q) {
        int chunk = wave * 4 + q;
        int col = chunk * 8 + (lane >> 3);
        pBq[q] = (const char*)WT + (size_t)(cbase + col) * (I_DIM * 2)
               + (size_t)k0 * 2 + (((lane & 7) ^ (lane >> 3)) << 4);
        ldsBo[q] = chunk * 1024;
    }

    f32x4 acc[4][4];
    #pragma unroll
    for (int m2 = 0; m2 < 4; ++m2)
        #pragma unroll
        for (int nn = 0; nn < 4; ++nn)
            acc[m2][nn] = (f32x4){0.f, 0.f, 0.f, 0.f};

    // ---- prologue: stage tile 0 into buffer 0
    {
        uint4 va[4]; uint32_t mk[4];
        #pragma unroll
        for (int p = 0; p < 4; ++p) { va[p] = *(const uint4*)pXA[p]; mk[p] = *pMA[p]; }
        #pragma unroll
        for (int q = 0; q < 4; ++q) async16((char*)sB[0] + ldsBo[q], pBq[q]);
        #pragma unroll
        for (int p = 0; p < 4; ++p) {
            uint4 z;
            z.x = va[p].x & bexp(mk[p], 0); z.y = va[p].y & bexp(mk[p], 1);
            z.z = va[p].z & bexp(mk[p], 2); z.w = va[p].w & bexp(mk[p], 3);
            *(uint4*)((char*)sA[0] + awz[p]) = z;
        }
        __syncthreads();
        #pragma unroll
        for (int p = 0; p < 4; ++p) { pXA[p] += 64; pMA[p] += 8; }
        #pragma unroll
        for (int q = 0; q < 4; ++q) pBq[q] += 128;
    }

    for (int kt = 0; kt < NT4; ++kt) {
        int cur = kt & 1;
        int nxt = cur ^ 1;
        bool pf = (kt + 1) < NT4;
        uint4 va[4]; uint32_t mk[4] = {0, 0, 0, 0};
        if (pf) {
            #pragma unroll
            for (int p = 0; p < 4; ++p) {
                va[p] = *(const uint4*)pXA[p]; mk[p] = *pMA[p];
                pXA[p] += 64; pMA[p] += 8;
            }
            #pragma unroll
            for (int q = 0; q < 4; ++q) {
                async16((char*)sB[nxt] + ldsBo[q], pBq[q]);
                pBq[q] += 128;
            }
        }
        // ---- compute current tile: 2 k-slices x 16 MFMA
        const char* sAc = (const char*)sA[cur];
        const char* sBc = (const char*)sB[cur];
        #pragma unroll
        for (int ks = 0; ks < 2; ++ks) {
            int kb = ks * 64 + (lgrp << 4);
            bf16x8 af[4], bfr[4];
            #pragma unroll
            for (int m2 = 0; m2 < 4; ++m2) {
                int row = wr * 64 + m2 * 16 + lrow;
                af[m2] = *(const bf16x8*)(sAc + row * 128 + (kb ^ ((row & 7) << 4)));
            }
            #pragma unroll
            for (int nn = 0; nn < 4; ++nn) {
                int col = wc * 64 + nn * 16 + lrow;
                bfr[nn] = *(const bf16x8*)(sBc + col * 128 + (kb ^ ((col & 7) << 4)));
            }
            #pragma unroll
            for (int m2 = 0; m2 < 4; ++m2)
                #pragma unroll
                for (int nn = 0; nn < 4; ++nn)
                    acc[m2][nn] = __builtin_amdgcn_mfma_f32_16x16x32_bf16(af[m2], bfr[nn], acc[m2][nn], 0, 0, 0);
        }
        // ---- finish staging next tile (A mask+write)
        if (pf) {
            #pragma unroll
            for (int p = 0; p < 4; ++p) {
                uint4 z;
                z.x = va[p].x & bexp(mk[p], 0); z.y = va[p].y & bexp(mk[p], 1);
                z.z = va[p].z & bexp(mk[p], 2); z.w = va[p].w & bexp(mk[p], 3);
                *(uint4*)((char*)sA[nxt] + awz[p]) = z;
            }
        }
        __syncthreads();
    }

    // ---- epilogue: raw f32 partials (out_mu added in k_reduce)
    #pragma unroll
    for (int nn = 0; nn < 4; ++nn) {
        int col = cbase + wc * 64 + nn * 16 + lrow;
        #pragma unroll
        for (int m2 = 0; m2 < 4; ++m2) {
            int rbase = r0 + wr * 64 + m2 * 16 + lgrp * 4;
            #pragma unroll
            for (int j = 0; j < 4; ++j)
                P[(size_t)(rbase + j) * OUT_DIM + col] = acc[m2][nn][j];
        }
    }
}

// ---------------- reduce: out = P0(out) + P1 + out_mu ------------------------
__global__ __launch_bounds__(256) void k_reduce(float* __restrict__ out,
                                                const float* __restrict__ P1,
                                                const float* __restrict__ out_mu) {
    int idx = blockIdx.x * 256 + threadIdx.x;       // float4 index, 1M total
    float4 a = ((const float4*)out)[idx];
    float4 b = ((const float4*)P1)[idx];
    float4 m = ((const float4*)out_mu)[idx & 1023];
    a.x += b.x + m.x; a.y += b.y + m.y; a.z += b.z + m.z; a.w += b.w + m.w;
    ((float4*)out)[idx] = a;
}

// ---------------- fallback main v3 (R3: 64x128 block, full K) ----------------
#define BM3 64
#define BN3 128
#define BK3 64

__global__ __launch_bounds__(512) void k_main3(const ushort* __restrict__ XB,
                                               const ushort* __restrict__ WT,
                                               const uint8_t* __restrict__ MB,
                                               const float* __restrict__ out_mu,
                                               float* __restrict__ out) {
    __shared__ ushort sA[2][BM3 * BK3];
    __shared__ ushort sB[2][BN3 * BK3];

    int bid  = blockIdx.x;
    int xcd  = bid & 7;
    int slot = bid >> 3;
    int n    = xcd * 4 + (slot >> 4);
    int mt   = slot & 15;
    int r0   = mt * BM3;
    int cbase = n * Q_DIM;

    int tid  = threadIdx.x;
    int lane = tid & 63;
    int wave = tid >> 6;
    int wr   = wave >> 2;
    int wc   = wave & 3;
    int lrow = lane & 15;
    int lgrp = lane >> 4;

    int arow  = tid >> 3;
    int akoff = (tid & 7) << 3;
    const ushort*  pXB = XB + (size_t)(r0 + arow) * I_DIM + akoff;
    const uint8_t* pMB = MB + ((size_t)n * R_TOTAL + (r0 + arow)) * 512 + (tid & 7);
    int aw = arow * 128 + ((akoff * 2) ^ ((arow & 7) << 4));

    int colA0 = wave * 16 + (lane >> 3);
    int kbB   = ((lane & 7) ^ (lane >> 3)) << 4;
    const char* pB0 = (const char*)(WT + (size_t)(cbase + colA0) * I_DIM) + kbB;
    const char* pB1 = pB0 + (size_t)8 * I_DIM * 2;

    f32x4 acc[2][2];
    #pragma unroll
    for (int m2 = 0; m2 < 2; ++m2)
        #pragma unroll
        for (int nn = 0; nn < 2; ++nn)
            acc[m2][nn] = (f32x4){0.f, 0.f, 0.f, 0.f};

    {
        uint4 va = *(const uint4*)pXB;
        uint32_t mb = *pMB;
        async16((char*)sB[0] + wave * 2048,        pB0);
        async16((char*)sB[0] + wave * 2048 + 1024, pB1);
        uint4 z;
        z.x = va.x & bexp(mb, 0); z.y = va.y & bexp(mb, 1);
        z.z = va.z & bexp(mb, 2); z.w = va.w & bexp(mb, 3);
        *(uint4*)((char*)sA[0] + aw) = z;
        __syncthreads();
        pXB += BK3; pMB += BK3 / 8; pB0 += BK3 * 2; pB1 += BK3 * 2;
    }

    const int NT = I_DIM / BK3;
    for (int kt = 0; kt < NT; ++kt) {
        int cur = kt & 1;
        int nxt = cur ^ 1;
        bool pf = (kt + 1) < NT;
        uint4 va; uint32_t mb = 0;
        if (pf) {
            va = *(const uint4*)pXB;
            mb = *pMB;
            async16((char*)sB[nxt] + wave * 2048,        pB0);
            async16((char*)sB[nxt] + wave * 2048 + 1024, pB1);
            pXB += BK3; pMB += BK3 / 8; pB0 += BK3 * 2; pB1 += BK3 * 2;
        }
        const char* sAc = (const char*)sA[cur];
        const char* sBc = (const char*)sB[cur];
        #pragma unroll
        for (int ks = 0; ks < 2; ++ks) {
            int kb = ks * 64 + (lgrp << 4);
            bf16x8 af[2], bfr[2];
            #pragma unroll
            for (int m2 = 0; m2 < 2; ++m2) {
                int row = wr * 32 + m2 * 16 + lrow;
                af[m2] = *(const bf16x8*)(sAc + row * 128 + (kb ^ ((row & 7) << 4)));
            }
            #pragma unroll
            for (int nn = 0; nn < 2; ++nn) {
                int col = wc * 32 + nn * 16 + lrow;
                bfr[nn] = *(const bf16x8*)(sBc + col * 128 + (kb ^ ((col & 7) << 4)));
            }
            #pragma unroll
            for (int m2 = 0; m2 < 2; ++m2)
                #pragma unroll
                for (int nn = 0; nn < 2; ++nn)
                    acc[m2][nn] = __builtin_amdgcn_mfma_f32_16x16x32_bf16(af[m2], bfr[nn], acc[m2][nn], 0, 0, 0);
        }
        if (pf) {
            uint4 z;
            z.x = va.x & bexp(mb, 0); z.y = va.y & bexp(mb, 1);
            z.z = va.z & bexp(mb, 2); z.w = va.w & bexp(mb, 3);
            *(uint4*)((char*)sA[nxt] + aw) = z;
        }
        __syncthreads();
    }

    #pragma unroll
    for (int nn = 0; nn < 2; ++nn) {
        int col = cbase + wc * 32 + nn * 16 + lrow;
        float om = out_mu[col];
        #pragma unroll
        for (int m2 = 0; m2 < 2; ++m2) {
            int rbase = r0 + wr * 32 + m2 * 16 + lgrp * 4;
            #pragma unroll
            for (int j = 0; j < 4; ++j)
                out[(size_t)(rbase + j) * OUT_DIM + col] = acc[m2][nn][j] + om;
        }
    }
}

// ---------------- fallback main v1 (reg-staged from fp32 x) ------------------
#define BM 128
#define BN 128
#define BK 64
__global__ __launch_bounds__(512) void k_main1(const float* __restrict__ x,
                                               const ushort* __restrict__ WT,
                                               const float* __restrict__ thT,
                                               const float* __restrict__ mu,
                                               const float* __restrict__ out_mu,
                                               float* __restrict__ out) {
    int bid  = blockIdx.x;
    int xcd  = bid & 7;
    int slot = bid >> 3;
    int n    = xcd * 4 + (slot >> 3);
    int mt   = slot & 7;
    int r0   = mt * BM;
    int cbase = n * Q_DIM;

    __shared__ ushort sA[BM * BK];
    __shared__ ushort sB[BN * BK];

    int tid  = threadIdx.x;
    int lane = tid & 63;
    int wave = tid >> 6;
    int wr   = wave >> 2;
    int wc   = wave & 3;

    f32x4 acc[4][2];
    #pragma unroll
    for (int m2 = 0; m2 < 4; ++m2)
        #pragma unroll
        for (int nn = 0; nn < 2; ++nn)
            acc[m2][nn] = (f32x4){0.f, 0.f, 0.f, 0.f};

    const int a_kq  = (tid & 15) * 4;
    const int a_rb  = tid >> 4;
    const int b_ko  = (tid & 7) * 8;
    const int b_cb  = tid >> 3;
    const int lrow  = lane & 15;
    const int lgrp  = lane >> 4;

    for (int kt = 0; kt < I_DIM / BK; ++kt) {
        int k0 = kt * BK;
        float4 thv = *(const float4*)(thT + (size_t)n * I_DIM + k0 + a_kq);
        float4 muv = *(const float4*)(mu + k0 + a_kq);
        #pragma unroll
        for (int p = 0; p < 4; ++p) {
            int row = a_rb + p * 32;
            float4 xv = *(const float4*)(x + (size_t)(r0 + row) * I_DIM + k0 + a_kq);
            float v0 = xv.x - muv.x, v1 = xv.y - muv.y, v2 = xv.z - muv.z, v3 = xv.w - muv.w;
            v0 = (fabsf(v0) >= thv.x) ? v0 : 0.f;
            v1 = (fabsf(v1) >= thv.y) ? v1 : 0.f;
            v2 = (fabsf(v2) >= thv.z) ? v2 : 0.f;
            v3 = (fabsf(v3) >= thv.w) ? v3 : 0.f;
            uint2 pk;
            pk.x = (uint32_t)f2bf(v0) | ((uint32_t)f2bf(v1) << 16);
            pk.y = (uint32_t)f2bf(v2) | ((uint32_t)f2bf(v3) << 16);
            int kbyte = (a_kq * 2) ^ ((row & 7) << 4);
            *(uint2*)((char*)sA + row * (BK * 2) + kbyte) = pk;
        }
        #pragma unroll
        for (int p = 0; p < 2; ++p) {
            int col = b_cb + p * 64;
            uint4 wv = *(const uint4*)(WT + (size_t)(cbase + col) * I_DIM + k0 + b_ko);
            int kbyte = (b_ko * 2) ^ ((col & 7) << 4);
            *(uint4*)((char*)sB + col * (BK * 2) + kbyte) = wv;
        }
        __syncthreads();
        #pragma unroll
        for (int ks = 0; ks < 2; ++ks) {
            int kb = ks * 64 + (lgrp << 4);
            bf16x8 af[4], bfr[2];
            #pragma unroll
            for (int m2 = 0; m2 < 4; ++m2) {
                int row = wr * 64 + m2 * 16 + lrow;
                af[m2] = *(const bf16x8*)((const char*)sA + row * (BK * 2) + (kb ^ ((row & 7) << 4)));
            }
            #pragma unroll
            for (int nn = 0; nn < 2; ++nn) {
                int col = wc * 32 + nn * 16 + lrow;
                bfr[nn] = *(const bf16x8*)((const char*)sB + col * (BK * 2) + (kb ^ ((col & 7) << 4)));
            }
            #pragma unroll
            for (int m2 = 0; m2 < 4; ++m2)
                #pragma unroll
                for (int nn = 0; nn < 2; ++nn)
                    acc[m2][nn] = __builtin_amdgcn_mfma_f32_16x16x32_bf16(af[m2], bfr[nn], acc[m2][nn], 0, 0, 0);
        }
        __syncthreads();
    }

    #pragma unroll
    for (int nn = 0; nn < 2; ++nn) {
        int col = cbase + wc * 32 + nn * 16 + lrow;
        float om = out_mu[col];
        #pragma unroll
        for (int m2 = 0; m2 < 4; ++m2) {
            int rbase = r0 + wr * 64 + m2 * 16 + lgrp * 4;
            #pragma unroll
            for (int j = 0; j < 4; ++j)
                out[(size_t)(rbase + j) * OUT_DIM + col] = acc[m2][nn][j] + om;
        }
    }
}

// ---------------- fallback: naive fp32 ---------------------------------------
__global__ __launch_bounds__(256) void k_naive(const float* __restrict__ x,
                                               const float* __restrict__ W,
                                               const float* __restrict__ th,
                                               const float* __restrict__ mu,
                                               const float* __restrict__ out_mu,
                                               float* __restrict__ out) {
    int idx = blockIdx.x * 256 + threadIdx.x;
    int r = idx >> 12;
    int c = idx & 4095;
    int n = c >> 7;
    float s = 0.f;
    for (int i = 0; i < I_DIM; ++i) {
        float xo = x[(size_t)r * I_DIM + i] - mu[i];
        if (fabsf(xo) >= th[i * N_STR + n])
            s += xo * W[(size_t)i * OUT_DIM + c];
    }
    out[idx] = s + out_mu[c];
}

extern "C" void kernel_launch(void* const* d_in, const int* in_sizes, int n_in,
                              void* d_out, int out_size, void* d_ws, size_t ws_size,
                              hipStream_t stream) {
    const float* x      = (const float*)d_in[0];
    const float* W      = (const float*)d_in[1];
    const float* th     = (const float*)d_in[2];
    const float* mu     = (const float*)d_in[3];
    const float* out_mu = (const float*)d_in[4];
    float* out = (float*)d_out;

    const size_t thT_b = (size_t)N_STR * I_DIM * sizeof(float);      // 0.5 MiB
    const size_t wT_b  = (size_t)OUT_DIM * I_DIM * sizeof(ushort);   // 32 MiB
    const size_t xb_b  = (size_t)R_TOTAL * I_DIM * sizeof(ushort);   // 8 MiB
    const size_t mb_b  = (size_t)N_STR * R_TOTAL * 512;              // 16 MiB
    const size_t p1_b  = (size_t)R_TOTAL * OUT_DIM * sizeof(float);  // 16 MiB

    ushort*  WT  = (ushort*)((char*)d_ws + thT_b);
    ushort*  XBp = (ushort*)((char*)d_ws + thT_b + wT_b);
    uint8_t* MBp = (uint8_t*)((char*)d_ws + thT_b + wT_b + xb_b);
    float*   P1  = (float*)((char*)d_ws + thT_b + wT_b + xb_b + mb_b);

    if (ws_size >= thT_b + wT_b + xb_b + mb_b + p1_b) {
        // fast path: merged pre-pass, split-K main, reduce
        k_prep3<<<4096 + 2048, 256, 0, stream>>>(W, WT, x, mu, th, XBp,
                                                 (unsigned long long*)MBp);
        k_main4<<<512, 256, 0, stream>>>(XBp, WT, MBp, out, P1);
        k_reduce<<<(R_TOTAL * OUT_DIM / 4) / 256, 256, 0, stream>>>(out, P1, out_mu);
    } else if (ws_size >= thT_b + wT_b + xb_b + mb_b) {
        k_prep2<<<2048, 256, 0, stream>>>(x, mu, th, XBp,
                                          (unsigned long long*)MBp);
        k_transpose_w<<<dim3(OUT_DIM / 64, I_DIM / 64), 256, 0, stream>>>(W, WT);
        k_main3<<<512, 512, 0, stream>>>(XBp, WT, MBp, out_mu, out);
    } else if (ws_size >= thT_b + wT_b) {
        float* thT = (float*)d_ws;
        k_transpose_th<<<(N_STR * I_DIM) / 256, 256, 0, stream>>>(th, thT);
        k_transpose_w<<<dim3(OUT_DIM / 64, I_DIM / 64), 256, 0, stream>>>(W, WT);
        k_main1<<<256, 512, 0, stream>>>(x, WT, thT, mu, out_mu, out);
    } else {
        k_naive<<<(R_TOTAL * OUT_DIM) / 256, 256, 0, stream>>>(x, W, th, mu, out_mu, out);
    }
}

// Round 5
// 108.958 us; speedup vs baseline: 1.0576x; 1.0576x over previous
//
#include <hip/hip_runtime.h>
#include <hip/hip_bf16.h>
#include <stdint.h>

// Problem dims (fixed by reference)
#define R_TOTAL 1024      // B*S
#define I_DIM   4096
#define OUT_DIM 4096
#define N_STR   32
#define Q_DIM   128

typedef __attribute__((ext_vector_type(8))) __bf16 bf16x8;
typedef __attribute__((ext_vector_type(4))) float  f32x4;

__device__ __forceinline__ ushort f2bf(float f) {
    uint32_t u = __float_as_uint(f);
    uint32_t r = (u + 0x7fffu + ((u >> 16) & 1u)) >> 16;   // RNE
    return (ushort)r;
}

// expand 2 mask bits (2w, 2w+1) -> 32-bit AND-mask for a packed bf16 pair
__device__ __forceinline__ uint32_t bexp(uint32_t b, int w) {
    return ((b >> (2 * w)) & 1u) * 0xFFFFu | ((b >> (2 * w + 1)) & 1u) * 0xFFFF0000u;
}

__device__ __forceinline__ void async16(void* lds, const void* g) {
    __builtin_amdgcn_global_load_lds(
        (const __attribute__((address_space(1))) unsigned int*)g,
        (__attribute__((address_space(3))) unsigned int*)lds, 16, 0, 0);
}

// ================= shared device bodies ======================================

// W [I][OUT] f32 -> WT [OUT][I] bf16, one 64x64 tile
__device__ __forceinline__ void transpose_w_block(const float* __restrict__ W,
                                                  ushort* __restrict__ WT,
                                                  int c0, int i0, int t,
                                                  float (*tile)[65]) {
    {
        int dc4 = (t & 15) * 4;
        int di  = t >> 4;
        #pragma unroll
        for (int p = 0; p < 4; ++p) {
            int ii = di + p * 16;
            float4 v = *(const float4*)(W + (size_t)(i0 + ii) * OUT_DIM + c0 + dc4);
            tile[ii][dc4 + 0] = v.x; tile[ii][dc4 + 1] = v.y;
            tile[ii][dc4 + 2] = v.z; tile[ii][dc4 + 3] = v.w;
        }
    }
    __syncthreads();
    {
        int iq = (t & 15) * 4;
        int dc = t >> 4;
        #pragma unroll
        for (int p = 0; p < 4; ++p) {
            int cc = dc + p * 16;
            ushort4 o;
            o.x = f2bf(tile[iq + 0][cc]);
            o.y = f2bf(tile[iq + 1][cc]);
            o.z = f2bf(tile[iq + 2][cc]);
            o.w = f2bf(tile[iq + 3][cc]);
            *(ushort4*)(WT + (size_t)(c0 + cc) * I_DIM + i0 + iq) = o;
        }
    }
}

// XB = bf16(x-mu) + per-stripe bitmasks, one (rb, ib) block of 8 rows x 256 i
// v2: XB gathered in LDS, written as coalesced uint4 (16 B/thread)
__device__ __forceinline__ void prep_block2(const float* __restrict__ x,
                                            const float* __restrict__ mu,
                                            const float* __restrict__ th,
                                            ushort* __restrict__ XB,
                                            unsigned long long* __restrict__ MB64,
                                            int rb, int ib, int tid,
                                            char* smem) {
    ushort* sXB = (ushort*)smem;                                  // 4 KB
    unsigned long long* sMB = (unsigned long long*)(smem + 4096); // 8 KB
    int i = ib * 256 + tid;
    int lane = tid & 63;
    int wave = tid >> 6;

    float muv = mu[i];
    float ax[8];
    #pragma unroll
    for (int rr = 0; rr < 8; ++rr) {
        int r = rb * 8 + rr;
        float xo = x[(size_t)r * I_DIM + i] - muv;
        sXB[rr * 256 + tid] = f2bf(xo);
        ax[rr] = fabsf(xo);
    }
    for (int n4 = 0; n4 < 8; ++n4) {
        float4 tv = *(const float4*)(th + (size_t)i * N_STR + n4 * 4);
        #pragma unroll
        for (int j = 0; j < 4; ++j) {
            float t = (j == 0) ? tv.x : (j == 1) ? tv.y : (j == 2) ? tv.z : tv.w;
            int n = n4 * 4 + j;
            #pragma unroll
            for (int rr = 0; rr < 8; ++rr) {
                unsigned long long bal = __ballot(ax[rr] >= t);
                if (lane == 0) sMB[(n * 8 + rr) * 4 + wave] = bal;
            }
        }
    }
    __syncthreads();
    // coalesced XB write: thread -> (row, 16B segment)
    {
        int row = tid >> 5, seg = tid & 31;
        uint4 v = *(const uint4*)&sXB[row * 256 + seg * 8];
        *(uint4*)(XB + (size_t)(rb * 8 + row) * I_DIM + ib * 256 + seg * 8) = v;
    }
    // coalesced mask write: thread -> (n, rr), 32 contiguous bytes
    {
        int n = tid >> 3, rr = tid & 7;
        const uint4* s = (const uint4*)&sMB[(n * 8 + rr) * 4];
        uint4* dst = (uint4*)((char*)MB64 + ((size_t)n * R_TOTAL + rb * 8 + rr) * 512 + ib * 32);
        dst[0] = s[0];
        dst[1] = s[1];
    }
}

// ---------------- merged pre-pass: transpose_w (0..4095) + prep (4096..6143) -
__global__ __launch_bounds__(256) void k_prep3(const float* __restrict__ W,
                                               ushort* __restrict__ WT,
                                               const float* __restrict__ x,
                                               const float* __restrict__ mu,
                                               const float* __restrict__ th,
                                               ushort* __restrict__ XB,
                                               unsigned long long* __restrict__ MB64) {
    __shared__ __align__(16) float smem[64 * 65];   // 16.25 KB, reused by both
    int b = blockIdx.x;
    int t = threadIdx.x;
    if (b < 4096) {
        transpose_w_block(W, WT, (b & 63) * 64, (b >> 6) * 64, t,
                          (float (*)[65])smem);
    } else {
        b -= 4096;                      // 0..2047
        prep_block2(x, mu, th, XB, MB64, b >> 4, b & 15, t, (char*)smem);
    }
}

// ---------------- standalone pre-passes (fallback path) ----------------------
__global__ __launch_bounds__(256) void k_transpose_th(const float* __restrict__ th,
                                                      float* __restrict__ thT) {
    int idx = blockIdx.x * 256 + threadIdx.x;
    int n = idx >> 12;
    int i = idx & 4095;
    thT[idx] = th[i * N_STR + n];
}

__global__ __launch_bounds__(256) void k_transpose_w(const float* __restrict__ W,
                                                     ushort* __restrict__ WT) {
    __shared__ float tile[64][65];
    transpose_w_block(W, WT, blockIdx.x * 64, blockIdx.y * 64, threadIdx.x, tile);
}

__global__ __launch_bounds__(256) void k_prep2(const float* __restrict__ x,
                                               const float* __restrict__ mu,
                                               const float* __restrict__ th,
                                               ushort* __restrict__ XB,
                                               unsigned long long* __restrict__ MB64) {
    __shared__ __align__(16) char smem[12288];
    prep_block2(x, mu, th, XB, MB64, blockIdx.x >> 4, blockIdx.x & 15,
                threadIdx.x, smem);
}

// ---------------- main v5: deep pipeline, tri-buf B, counted vmcnt -----------
// tile 128x128, 4 waves of 64x64, BK=64, split-K=2, grid 512, 2 blocks/CU.
// Raw s_barrier + counted s_waitcnt: B DMA issued 2 tiles ahead stays in
// flight across barriers (T3/T4 minimum); A regs loaded 2 tiles ahead.
#define NT5 32   // K-steps per block (K=2048 per k-half)

__global__ __launch_bounds__(256, 2) void k_main5(const ushort* __restrict__ XB,
                                                  const ushort* __restrict__ WT,
                                                  const uint8_t* __restrict__ MB,
                                                  float* __restrict__ P0,
                                                  float* __restrict__ P1) {
    __shared__ ushort sA[2][128 * 64];   // 16 KB each
    __shared__ ushort sB[3][128 * 64];   // 16 KB each  (total 80 KB)

    int bid  = blockIdx.x;               // 0..511
    int xcd  = bid & 7;
    int slot = bid >> 3;                 // 0..63
    int n    = xcd * 4 + (slot & 3);     // stripe (XCD-local group of 4)
    int rt   = (slot >> 2) & 7;          // row tile 0..7
    int kh   = slot >> 5;                // k-half 0..1
    int r0   = rt * 128;
    int k0   = kh * 2048;                // element offset in K
    int cbase = n * Q_DIM;
    float* P = kh ? P1 : P0;

    int tid  = threadIdx.x;
    int lane = tid & 63;
    int wave = tid >> 6;                 // 0..3
    int wr   = wave >> 1;                // 0..1 : 64-row group
    int wc   = wave & 1;                 // 0..1 : 64-col group
    int lrow = lane & 15;
    int lgrp = lane >> 4;

    // ---- A staging maps: pass p: row = p*32 + (tid>>3), 8 elems at (tid&7)*8
    const ushort*  pXA[4];
    const uint8_t* pMA[4];
    int awz[4];
    {
        int ar = tid >> 3;
        int ak = (tid & 7) * 8;
        #pragma unroll
        for (int p = 0; p < 4; ++p) {
            int row = p * 32 + ar;
            pXA[p] = XB + (size_t)(r0 + row) * I_DIM + k0 + ak;
            pMA[p] = MB + ((size_t)n * R_TOTAL + r0 + row) * 512 + (k0 >> 3) + (tid & 7);
            awz[p] = row * 128 + ((ak * 2) ^ ((row & 7) << 4));
        }
    }

    // ---- B staging maps (global_load_lds, pre-swizzled source)
    const char* pBq[4];
    int ldsBo[4];
    #pragma unroll
    for (int q = 0; q < 4; ++q) {
        int chunk = wave * 4 + q;
        int col = chunk * 8 + (lane >> 3);
        pBq[q] = (const char*)WT + (size_t)(cbase + col) * (I_DIM * 2)
               + (size_t)k0 * 2 + (((lane & 7) ^ (lane >> 3)) << 4);
        ldsBo[q] = chunk * 1024;
    }

    f32x4 acc[4][4];
    #pragma unroll
    for (int m2 = 0; m2 < 4; ++m2)
        #pragma unroll
        for (int nn = 0; nn < 4; ++nn)
            acc[m2][nn] = (f32x4){0.f, 0.f, 0.f, 0.f};

    uint4 va[4]; uint32_t mk[4];

    // ---- prologue: B0,B1 in flight; A0 masked+written; A1 in regs
    #pragma unroll
    for (int q = 0; q < 4; ++q) { async16((char*)sB[0] + ldsBo[q], pBq[q]); pBq[q] += 128; }
    #pragma unroll
    for (int q = 0; q < 4; ++q) { async16((char*)sB[1] + ldsBo[q], pBq[q]); pBq[q] += 128; }
    #pragma unroll
    for (int p = 0; p < 4; ++p) { va[p] = *(const uint4*)pXA[p]; mk[p] = *pMA[p];
                                  pXA[p] += 64; pMA[p] += 8; }
    #pragma unroll
    for (int p = 0; p < 4; ++p) {
        uint4 z;
        z.x = va[p].x & bexp(mk[p], 0); z.y = va[p].y & bexp(mk[p], 1);
        z.z = va[p].z & bexp(mk[p], 2); z.w = va[p].w & bexp(mk[p], 3);
        *(uint4*)((char*)sA[0] + awz[p]) = z;
    }
    #pragma unroll
    for (int p = 0; p < 4; ++p) { va[p] = *(const uint4*)pXA[p]; mk[p] = *pMA[p];
                                  pXA[p] += 64; pMA[p] += 8; }
    asm volatile("s_waitcnt lgkmcnt(0)" ::: "memory");
    __builtin_amdgcn_s_barrier();

    for (int t = 0; t < NT5; ++t) {
        // issue B(t+2) DMA (stays in flight across the barrier)
        if (t + 2 < NT5) {
            int buf = (t + 2) % 3;
            #pragma unroll
            for (int q = 0; q < 4; ++q) {
                async16((char*)sB[buf] + ldsBo[q], pBq[q]);
                pBq[q] += 128;
            }
        }
        // ---- compute tile t
        const char* sAc = (const char*)sA[t & 1];
        const char* sBc = (const char*)sB[t % 3];
        __builtin_amdgcn_s_setprio(1);
        #pragma unroll
        for (int ks = 0; ks < 2; ++ks) {
            int kb = ks * 64 + (lgrp << 4);
            bf16x8 af[4], bfr[4];
            #pragma unroll
            for (int m2 = 0; m2 < 4; ++m2) {
                int row = wr * 64 + m2 * 16 + lrow;
                af[m2] = *(const bf16x8*)(sAc + row * 128 + (kb ^ ((row & 7) << 4)));
            }
            #pragma unroll
            for (int nn = 0; nn < 4; ++nn) {
                int col = wc * 64 + nn * 16 + lrow;
                bfr[nn] = *(const bf16x8*)(sBc + col * 128 + (kb ^ ((col & 7) << 4)));
            }
            #pragma unroll
            for (int m2 = 0; m2 < 4; ++m2)
                #pragma unroll
                for (int nn = 0; nn < 4; ++nn)
                    acc[m2][nn] = __builtin_amdgcn_mfma_f32_16x16x32_bf16(af[m2], bfr[nn], acc[m2][nn], 0, 0, 0);
        }
        __builtin_amdgcn_s_setprio(0);
        // ---- mask + write A(t+1) into the other sA buffer
        if (t + 1 < NT5) {
            #pragma unroll
            for (int p = 0; p < 4; ++p) {
                uint4 z;
                z.x = va[p].x & bexp(mk[p], 0); z.y = va[p].y & bexp(mk[p], 1);
                z.z = va[p].z & bexp(mk[p], 2); z.w = va[p].w & bexp(mk[p], 3);
                *(uint4*)((char*)sA[(t + 1) & 1] + awz[p]) = z;
            }
        }
        // B(t+1) guaranteed landed after this (keeps B(t+2) in flight)
        asm volatile("s_waitcnt vmcnt(4)" ::: "memory");
        // ---- load A(t+2) regs (consumed next step)
        if (t + 2 < NT5) {
            #pragma unroll
            for (int p = 0; p < 4; ++p) { va[p] = *(const uint4*)pXA[p]; mk[p] = *pMA[p];
                                          pXA[p] += 64; pMA[p] += 8; }
        }
        asm volatile("s_waitcnt lgkmcnt(0)" ::: "memory");
        __builtin_amdgcn_s_barrier();
    }

    // ---- epilogue: raw f32 partials (out_mu added in k_reduce)
    #pragma unroll
    for (int nn = 0; nn < 4; ++nn) {
        int col = cbase + wc * 64 + nn * 16 + lrow;
        #pragma unroll
        for (int m2 = 0; m2 < 4; ++m2) {
            int rbase = r0 + wr * 64 + m2 * 16 + lgrp * 4;
            #pragma unroll
            for (int j = 0; j < 4; ++j)
                P[(size_t)(rbase + j) * OUT_DIM + col] = acc[m2][nn][j];
        }
    }
}

// ---------------- reduce: out = P0(out) + P1 + out_mu ------------------------
__global__ __launch_bounds__(256) void k_reduce(float* __restrict__ out,
                                                const float* __restrict__ P1,
                                                const float* __restrict__ out_mu) {
    int idx = blockIdx.x * 256 + threadIdx.x;       // float4 index, 1M total
    float4 a = ((const float4*)out)[idx];
    float4 b = ((const float4*)P1)[idx];
    float4 m = ((const float4*)out_mu)[idx & 1023];
    a.x += b.x + m.x; a.y += b.y + m.y; a.z += b.z + m.z; a.w += b.w + m.w;
    ((float4*)out)[idx] = a;
}

// ---------------- fallback main v3 (R3: 64x128 block, full K) ----------------
#define BM3 64
#define BN3 128
#define BK3 64

__global__ __launch_bounds__(512) void k_main3(const ushort* __restrict__ XB,
                                               const ushort* __restrict__ WT,
                                               const uint8_t* __restrict__ MB,
                                               const float* __restrict__ out_mu,
                                               float* __restrict__ out) {
    __shared__ ushort sA[2][BM3 * BK3];
    __shared__ ushort sB[2][BN3 * BK3];

    int bid  = blockIdx.x;
    int xcd  = bid & 7;
    int slot = bid >> 3;
    int n    = xcd * 4 + (slot >> 4);
    int mt   = slot & 15;
    int r0   = mt * BM3;
    int cbase = n * Q_DIM;

    int tid  = threadIdx.x;
    int lane = tid & 63;
    int wave = tid >> 6;
    int wr   = wave >> 2;
    int wc   = wave & 3;
    int lrow = lane & 15;
    int lgrp = lane >> 4;

    int arow  = tid >> 3;
    int akoff = (tid & 7) << 3;
    const ushort*  pXB = XB + (size_t)(r0 + arow) * I_DIM + akoff;
    const uint8_t* pMB = MB + ((size_t)n * R_TOTAL + (r0 + arow)) * 512 + (tid & 7);
    int aw = arow * 128 + ((akoff * 2) ^ ((arow & 7) << 4));

    int colA0 = wave * 16 + (lane >> 3);
    int kbB   = ((lane & 7) ^ (lane >> 3)) << 4;
    const char* pB0 = (const char*)(WT + (size_t)(cbase + colA0) * I_DIM) + kbB;
    const char* pB1 = pB0 + (size_t)8 * I_DIM * 2;

    f32x4 acc[2][2];
    #pragma unroll
    for (int m2 = 0; m2 < 2; ++m2)
        #pragma unroll
        for (int nn = 0; nn < 2; ++nn)
            acc[m2][nn] = (f32x4){0.f, 0.f, 0.f, 0.f};

    {
        uint4 va = *(const uint4*)pXB;
        uint32_t mb = *pMB;
        async16((char*)sB[0] + wave * 2048,        pB0);
        async16((char*)sB[0] + wave * 2048 + 1024, pB1);
        uint4 z;
        z.x = va.x & bexp(mb, 0); z.y = va.y & bexp(mb, 1);
        z.z = va.z & bexp(mb, 2); z.w = va.w & bexp(mb, 3);
        *(uint4*)((char*)sA[0] + aw) = z;
        __syncthreads();
        pXB += BK3; pMB += BK3 / 8; pB0 += BK3 * 2; pB1 += BK3 * 2;
    }

    const int NT = I_DIM / BK3;
    for (int kt = 0; kt < NT; ++kt) {
        int cur = kt & 1;
        int nxt = cur ^ 1;
        bool pf = (kt + 1) < NT;
        uint4 va; uint32_t mb = 0;
        if (pf) {
            va = *(const uint4*)pXB;
            mb = *pMB;
            async16((char*)sB[nxt] + wave * 2048,        pB0);
            async16((char*)sB[nxt] + wave * 2048 + 1024, pB1);
            pXB += BK3; pMB += BK3 / 8; pB0 += BK3 * 2; pB1 += BK3 * 2;
        }
        const char* sAc = (const char*)sA[cur];
        const char* sBc = (const char*)sB[cur];
        #pragma unroll
        for (int ks = 0; ks < 2; ++ks) {
            int kb = ks * 64 + (lgrp << 4);
            bf16x8 af[2], bfr[2];
            #pragma unroll
            for (int m2 = 0; m2 < 2; ++m2) {
                int row = wr * 32 + m2 * 16 + lrow;
                af[m2] = *(const bf16x8*)(sAc + row * 128 + (kb ^ ((row & 7) << 4)));
            }
            #pragma unroll
            for (int nn = 0; nn < 2; ++nn) {
                int col = wc * 32 + nn * 16 + lrow;
                bfr[nn] = *(const bf16x8*)(sBc + col * 128 + (kb ^ ((col & 7) << 4)));
            }
            #pragma unroll
            for (int m2 = 0; m2 < 2; ++m2)
                #pragma unroll
                for (int nn = 0; nn < 2; ++nn)
                    acc[m2][nn] = __builtin_amdgcn_mfma_f32_16x16x32_bf16(af[m2], bfr[nn], acc[m2][nn], 0, 0, 0);
        }
        if (pf) {
            uint4 z;
            z.x = va.x & bexp(mb, 0); z.y = va.y & bexp(mb, 1);
            z.z = va.z & bexp(mb, 2); z.w = va.w & bexp(mb, 3);
            *(uint4*)((char*)sA[nxt] + aw) = z;
        }
        __syncthreads();
    }

    #pragma unroll
    for (int nn = 0; nn < 2; ++nn) {
        int col = cbase + wc * 32 + nn * 16 + lrow;
        float om = out_mu[col];
        #pragma unroll
        for (int m2 = 0; m2 < 2; ++m2) {
            int rbase = r0 + wr * 32 + m2 * 16 + lgrp * 4;
            #pragma unroll
            for (int j = 0; j < 4; ++j)
                out[(size_t)(rbase + j) * OUT_DIM + col] = acc[m2][nn][j] + om;
        }
    }
}

// ---------------- fallback main v1 (reg-staged from fp32 x) ------------------
#define BM 128
#define BN 128
#define BK 64
__global__ __launch_bounds__(512) void k_main1(const float* __restrict__ x,
                                               const ushort* __restrict__ WT,
                                               const float* __restrict__ thT,
                                               const float* __restrict__ mu,
                                               const float* __restrict__ out_mu,
                                               float* __restrict__ out) {
    int bid  = blockIdx.x;
    int xcd  = bid & 7;
    int slot = bid >> 3;
    int n    = xcd * 4 + (slot >> 3);
    int mt   = slot & 7;
    int r0   = mt * BM;
    int cbase = n * Q_DIM;

    __shared__ ushort sA[BM * BK];
    __shared__ ushort sB[BN * BK];

    int tid  = threadIdx.x;
    int lane = tid & 63;
    int wave = tid >> 6;
    int wr   = wave >> 2;
    int wc   = wave & 3;

    f32x4 acc[4][2];
    #pragma unroll
    for (int m2 = 0; m2 < 4; ++m2)
        #pragma unroll
        for (int nn = 0; nn < 2; ++nn)
            acc[m2][nn] = (f32x4){0.f, 0.f, 0.f, 0.f};

    const int a_kq  = (tid & 15) * 4;
    const int a_rb  = tid >> 4;
    const int b_ko  = (tid & 7) * 8;
    const int b_cb  = tid >> 3;
    const int lrow  = lane & 15;
    const int lgrp  = lane >> 4;

    for (int kt = 0; kt < I_DIM / BK; ++kt) {
        int k0 = kt * BK;
        float4 thv = *(const float4*)(thT + (size_t)n * I_DIM + k0 + a_kq);
        float4 muv = *(const float4*)(mu + k0 + a_kq);
        #pragma unroll
        for (int p = 0; p < 4; ++p) {
            int row = a_rb + p * 32;
            float4 xv = *(const float4*)(x + (size_t)(r0 + row) * I_DIM + k0 + a_kq);
            float v0 = xv.x - muv.x, v1 = xv.y - muv.y, v2 = xv.z - muv.z, v3 = xv.w - muv.w;
            v0 = (fabsf(v0) >= thv.x) ? v0 : 0.f;
            v1 = (fabsf(v1) >= thv.y) ? v1 : 0.f;
            v2 = (fabsf(v2) >= thv.z) ? v2 : 0.f;
            v3 = (fabsf(v3) >= thv.w) ? v3 : 0.f;
            uint2 pk;
            pk.x = (uint32_t)f2bf(v0) | ((uint32_t)f2bf(v1) << 16);
            pk.y = (uint32_t)f2bf(v2) | ((uint32_t)f2bf(v3) << 16);
            int kbyte = (a_kq * 2) ^ ((row & 7) << 4);
            *(uint2*)((char*)sA + row * (BK * 2) + kbyte) = pk;
        }
        #pragma unroll
        for (int p = 0; p < 2; ++p) {
            int col = b_cb + p * 64;
            uint4 wv = *(const uint4*)(WT + (size_t)(cbase + col) * I_DIM + k0 + b_ko);
            int kbyte = (b_ko * 2) ^ ((col & 7) << 4);
            *(uint4*)((char*)sB + col * (BK * 2) + kbyte) = wv;
        }
        __syncthreads();
        #pragma unroll
        for (int ks = 0; ks < 2; ++ks) {
            int kb = ks * 64 + (lgrp << 4);
            bf16x8 af[4], bfr[2];
            #pragma unroll
            for (int m2 = 0; m2 < 4; ++m2) {
                int row = wr * 64 + m2 * 16 + lrow;
                af[m2] = *(const bf16x8*)((const char*)sA + row * (BK * 2) + (kb ^ ((row & 7) << 4)));
            }
            #pragma unroll
            for (int nn = 0; nn < 2; ++nn) {
                int col = wc * 32 + nn * 16 + lrow;
                bfr[nn] = *(const bf16x8*)((const char*)sB + col * (BK * 2) + (kb ^ ((col & 7) << 4)));
            }
            #pragma unroll
            for (int m2 = 0; m2 < 4; ++m2)
                #pragma unroll
                for (int nn = 0; nn < 2; ++nn)
                    acc[m2][nn] = __builtin_amdgcn_mfma_f32_16x16x32_bf16(af[m2], bfr[nn], acc[m2][nn], 0, 0, 0);
        }
        __syncthreads();
    }

    #pragma unroll
    for (int nn = 0; nn < 2; ++nn) {
        int col = cbase + wc * 32 + nn * 16 + lrow;
        float om = out_mu[col];
        #pragma unroll
        for (int m2 = 0; m2 < 4; ++m2) {
            int rbase = r0 + wr * 64 + m2 * 16 + lgrp * 4;
            #pragma unroll
            for (int j = 0; j < 4; ++j)
                out[(size_t)(rbase + j) * OUT_DIM + col] = acc[m2][nn][j] + om;
        }
    }
}

// ---------------- fallback: naive fp32 ---------------------------------------
__global__ __launch_bounds__(256) void k_naive(const float* __restrict__ x,
                                               const float* __restrict__ W,
                                               const float* __restrict__ th,
                                               const float* __restrict__ mu,
                                               const float* __restrict__ out_mu,
                                               float* __restrict__ out) {
    int idx = blockIdx.x * 256 + threadIdx.x;
    int r = idx >> 12;
    int c = idx & 4095;
    int n = c >> 7;
    float s = 0.f;
    for (int i = 0; i < I_DIM; ++i) {
        float xo = x[(size_t)r * I_DIM + i] - mu[i];
        if (fabsf(xo) >= th[i * N_STR + n])
            s += xo * W[(size_t)i * OUT_DIM + c];
    }
    out[idx] = s + out_mu[c];
}

extern "C" void kernel_launch(void* const* d_in, const int* in_sizes, int n_in,
                              void* d_out, int out_size, void* d_ws, size_t ws_size,
                              hipStream_t stream) {
    const float* x      = (const float*)d_in[0];
    const float* W      = (const float*)d_in[1];
    const float* th     = (const float*)d_in[2];
    const float* mu     = (const float*)d_in[3];
    const float* out_mu = (const float*)d_in[4];
    float* out = (float*)d_out;

    const size_t thT_b = (size_t)N_STR * I_DIM * sizeof(float);      // 0.5 MiB
    const size_t wT_b  = (size_t)OUT_DIM * I_DIM * sizeof(ushort);   // 32 MiB
    const size_t xb_b  = (size_t)R_TOTAL * I_DIM * sizeof(ushort);   // 8 MiB
    const size_t mb_b  = (size_t)N_STR * R_TOTAL * 512;              // 16 MiB
    const size_t p1_b  = (size_t)R_TOTAL * OUT_DIM * sizeof(float);  // 16 MiB

    ushort*  WT  = (ushort*)((char*)d_ws + thT_b);
    ushort*  XBp = (ushort*)((char*)d_ws + thT_b + wT_b);
    uint8_t* MBp = (uint8_t*)((char*)d_ws + thT_b + wT_b + xb_b);
    float*   P1  = (float*)((char*)d_ws + thT_b + wT_b + xb_b + mb_b);

    if (ws_size >= thT_b + wT_b + xb_b + mb_b + p1_b) {
        // fast path: merged pre-pass, deep-pipelined split-K main, reduce
        k_prep3<<<4096 + 2048, 256, 0, stream>>>(W, WT, x, mu, th, XBp,
                                                 (unsigned long long*)MBp);
        k_main5<<<512, 256, 0, stream>>>(XBp, WT, MBp, out, P1);
        k_reduce<<<(R_TOTAL * OUT_DIM / 4) / 256, 256, 0, stream>>>(out, P1, out_mu);
    } else if (ws_size >= thT_b + wT_b + xb_b + mb_b) {
        k_prep2<<<2048, 256, 0, stream>>>(x, mu, th, XBp,
                                          (unsigned long long*)MBp);
        k_transpose_w<<<dim3(OUT_DIM / 64, I_DIM / 64), 256, 0, stream>>>(W, WT);
        k_main3<<<512, 512, 0, stream>>>(XBp, WT, MBp, out_mu, out);
    } else if (ws_size >= thT_b + wT_b) {
        float* thT = (float*)d_ws;
        k_transpose_th<<<(N_STR * I_DIM) / 256, 256, 0, stream>>>(th, thT);
        k_transpose_w<<<dim3(OUT_DIM / 64, I_DIM / 64), 256, 0, stream>>>(W, WT);
        k_main1<<<256, 512, 0, stream>>>(x, WT, thT, mu, out_mu, out);
    } else {
        k_naive<<<(R_TOTAL * OUT_DIM) / 256, 256, 0, stream>>>(x, W, th, mu, out_mu, out);
    }
}